// Round 1
// baseline (575.430 us; speedup 1.0000x reference)
//
#include <hip/hip_runtime.h>

#define HH 512
#define WW 512
#define CIN 3
#define COUT 32
#define NB 16

typedef float f4 __attribute__((ext_vector_type(4)));

// Block: (64,4). Each thread: 4 consecutive x pixels, all 32 output channels.
// Grid: (2, 128, 16) -> x: 2*64*4=512, y: 128*4=512, z: batch.
//
// Weights are wave-uniform: tap weights are read straight from Wg with
// uniform addresses so they land in SGPRs via s_load (no LDS, no VMEM in
// the inner loop). Only the folded center weight (-sum of neighbor taps,
// per channel) + bias live in LDS: 4 floats per o, one broadcast
// ds_read_b128 per o-iteration (32 LDS ops/thread vs ~900 before).
__global__ __launch_bounds__(256)
void pointconv_kernel(const float* __restrict__ x,
                      const float* __restrict__ Wg,
                      const float* __restrict__ bias,
                      float* __restrict__ out) {
    // Cb[o*4 + c] = -sum_k Wg[o,k,c]  (center tap), Cb[o*4+3] = bias[o]
    __shared__ float Cb[COUT * 4];

    const int tid = threadIdx.y * 64 + threadIdx.x;
    if (tid < COUT) {
        const int o = tid;
        float cs0 = 0.f, cs1 = 0.f, cs2 = 0.f;
        #pragma unroll
        for (int k = 0; k < 8; ++k) {
            cs0 += Wg[o * 24 + k * 3 + 0];
            cs1 += Wg[o * 24 + k * 3 + 1];
            cs2 += Wg[o * 24 + k * 3 + 2];
        }
        Cb[o * 4 + 0] = -cs0;
        Cb[o * 4 + 1] = -cs1;
        Cb[o * 4 + 2] = -cs2;
        Cb[o * 4 + 3] = bias[o];
    }
    __syncthreads();

    const int b  = blockIdx.z;
    const int y  = blockIdx.y * 4 + threadIdx.y;
    const int x0 = (blockIdx.x * 64 + threadIdx.x) * 4;

    // Stage 3 channels x 3 rows x 6 cols (x0-1 .. x0+4) into registers.
    float v[3][3][6];
    #pragma unroll
    for (int c = 0; c < 3; ++c) {
        const float* xc = x + ((size_t)(b * CIN + c) * HH) * WW;
        #pragma unroll
        for (int r = 0; r < 3; ++r) {
            const int yy = y + r - 1;
            const bool rowok = (yy >= 0) && (yy < HH);
            const float* row = xc + (ptrdiff_t)yy * WW;
            f4 mid;
            if (rowok) {
                mid = *(const f4*)(row + x0);
            } else {
                mid = (f4){0.f, 0.f, 0.f, 0.f};
            }
            v[c][r][1] = mid.x; v[c][r][2] = mid.y;
            v[c][r][3] = mid.z; v[c][r][4] = mid.w;
            v[c][r][0] = (rowok && x0 > 0)        ? row[x0 - 1] : 0.f;
            v[c][r][5] = (rowok && x0 + 4 < WW)   ? row[x0 + 4] : 0.f;
        }
    }

    float* outp = out + (((size_t)b * COUT) * HH + y) * WW + x0;

    // COORDS k -> (row i, col j) within the 3x3 window (center excluded).
    const int TI[8] = {0, 1, 2, 0, 2, 0, 1, 2};
    const int TJ[8] = {0, 0, 0, 1, 1, 2, 2, 2};

    #pragma unroll 2
    for (int o = 0; o < COUT; ++o) {
        const float* wo = Wg + o * 24;        // wave-uniform -> s_load
        const f4 cb = *(const f4*)&Cb[o * 4]; // one broadcast ds_read_b128

        float a0 = cb.w, a1 = cb.w, a2 = cb.w, a3 = cb.w;
        #pragma unroll
        for (int k = 0; k < 8; ++k) {
            const int ty = TI[k], tx = TJ[k];
            #pragma unroll
            for (int c = 0; c < 3; ++c) {
                const float w = wo[k * 3 + c]; // uniform (SGPR operand)
                a0 += w * v[c][ty][0 + tx];
                a1 += w * v[c][ty][1 + tx];
                a2 += w * v[c][ty][2 + tx];
                a3 += w * v[c][ty][3 + tx];
            }
        }
        // Center taps: w_c = -sum of neighbors (from Cb), pixel cols 1..4.
        {
            a0 += cb.x * v[0][1][1]; a1 += cb.x * v[0][1][2];
            a2 += cb.x * v[0][1][3]; a3 += cb.x * v[0][1][4];
            a0 += cb.y * v[1][1][1]; a1 += cb.y * v[1][1][2];
            a2 += cb.y * v[1][1][3]; a3 += cb.y * v[1][1][4];
            a0 += cb.z * v[2][1][1]; a1 += cb.z * v[2][1][2];
            a2 += cb.z * v[2][1][3]; a3 += cb.z * v[2][1][4];
        }
        f4 res = (f4){a0, a1, a2, a3};
        __builtin_nontemporal_store(res, (f4*)(outp + (size_t)o * (HH * WW)));
    }
}

extern "C" void kernel_launch(void* const* d_in, const int* in_sizes, int n_in,
                              void* d_out, int out_size, void* d_ws, size_t ws_size,
                              hipStream_t stream) {
    const float* x    = (const float*)d_in[0];
    const float* Wg   = (const float*)d_in[1];
    const float* bias = (const float*)d_in[2];
    float* out = (float*)d_out;

    dim3 block(64, 4, 1);
    dim3 grid(2, 128, 16);
    hipLaunchKernelGGL(pointconv_kernel, grid, block, 0, stream, x, Wg, bias, out);
}

// Round 2
// 565.279 us; speedup vs baseline: 1.0180x; 1.0180x over previous
//
#include <hip/hip_runtime.h>

#define HH 512
#define WW 512
#define CIN 3
#define COUT 32
#define NB 16

typedef float f4 __attribute__((ext_vector_type(4)));

// Block: (128,2) = 256 threads. Each thread: 4 consecutive x pixels, all 32
// output channels. One block owns the FULL 512-px row width and 2 adjacent
// rows, so each o-iteration stores 4 KB contiguous (2 rows x 2 KB, rows are
// adjacent in memory) -> good DRAM page locality. Plain stores (no nt) so L2
// aggregates writebacks; the 6.3 TB/s fill kernel proves this path's ceiling.
// Grid: (1, 256, 16) -> y: 256*2=512, z: batch.
//
// Tap weights are wave-uniform: read via uniform addresses -> s_load into
// SGPRs (v_fma takes one SGPR operand; zero LDS/VMEM in the FMA loop). Only
// folded center weights (-sum of neighbors, per channel) + bias are in LDS:
// one broadcast ds_read_b128 per o.
__global__ __launch_bounds__(256)
void pointconv_kernel(const float* __restrict__ x,
                      const float* __restrict__ Wg,
                      const float* __restrict__ bias,
                      float* __restrict__ out) {
    // Cb[o*4 + c] = -sum_k Wg[o,k,c]  (center tap), Cb[o*4+3] = bias[o]
    __shared__ float Cb[COUT * 4];

    const int tid = threadIdx.y * 128 + threadIdx.x;
    if (tid < COUT) {
        const int o = tid;
        float cs0 = 0.f, cs1 = 0.f, cs2 = 0.f;
        #pragma unroll
        for (int k = 0; k < 8; ++k) {
            cs0 += Wg[o * 24 + k * 3 + 0];
            cs1 += Wg[o * 24 + k * 3 + 1];
            cs2 += Wg[o * 24 + k * 3 + 2];
        }
        Cb[o * 4 + 0] = -cs0;
        Cb[o * 4 + 1] = -cs1;
        Cb[o * 4 + 2] = -cs2;
        Cb[o * 4 + 3] = bias[o];
    }
    __syncthreads();

    const int b  = blockIdx.z;
    const int y  = blockIdx.y * 2 + threadIdx.y;
    const int x0 = threadIdx.x * 4;

    // Stage 3 channels x 3 rows x 6 cols (x0-1 .. x0+4) into registers.
    float v[3][3][6];
    #pragma unroll
    for (int c = 0; c < 3; ++c) {
        const float* xc = x + ((size_t)(b * CIN + c) * HH) * WW;
        #pragma unroll
        for (int r = 0; r < 3; ++r) {
            const int yy = y + r - 1;
            const bool rowok = (yy >= 0) && (yy < HH);
            const float* row = xc + (ptrdiff_t)yy * WW;
            f4 mid;
            if (rowok) {
                mid = *(const f4*)(row + x0);
            } else {
                mid = (f4){0.f, 0.f, 0.f, 0.f};
            }
            v[c][r][1] = mid.x; v[c][r][2] = mid.y;
            v[c][r][3] = mid.z; v[c][r][4] = mid.w;
            v[c][r][0] = (rowok && x0 > 0)        ? row[x0 - 1] : 0.f;
            v[c][r][5] = (rowok && x0 + 4 < WW)   ? row[x0 + 4] : 0.f;
        }
    }

    float* outp = out + (((size_t)b * COUT) * HH + y) * WW + x0;

    // COORDS k -> (row i, col j) within the 3x3 window (center excluded).
    const int TI[8] = {0, 1, 2, 0, 2, 0, 1, 2};
    const int TJ[8] = {0, 0, 0, 1, 1, 2, 2, 2};

    #pragma unroll 2
    for (int o = 0; o < COUT; ++o) {
        const float* wo = Wg + o * 24;        // wave-uniform -> s_load
        const f4 cb = *(const f4*)&Cb[o * 4]; // one broadcast ds_read_b128

        float a0 = cb.w, a1 = cb.w, a2 = cb.w, a3 = cb.w;
        #pragma unroll
        for (int k = 0; k < 8; ++k) {
            const int ty = TI[k], tx = TJ[k];
            #pragma unroll
            for (int c = 0; c < 3; ++c) {
                const float w = wo[k * 3 + c]; // uniform (SGPR operand)
                a0 += w * v[c][ty][0 + tx];
                a1 += w * v[c][ty][1 + tx];
                a2 += w * v[c][ty][2 + tx];
                a3 += w * v[c][ty][3 + tx];
            }
        }
        // Center taps: w_c = -sum of neighbors (from Cb), pixel cols 1..4.
        a0 += cb.x * v[0][1][1]; a1 += cb.x * v[0][1][2];
        a2 += cb.x * v[0][1][3]; a3 += cb.x * v[0][1][4];
        a0 += cb.y * v[1][1][1]; a1 += cb.y * v[1][1][2];
        a2 += cb.y * v[1][1][3]; a3 += cb.y * v[1][1][4];
        a0 += cb.z * v[2][1][1]; a1 += cb.z * v[2][1][2];
        a2 += cb.z * v[2][1][3]; a3 += cb.z * v[2][1][4];

        f4 res = (f4){a0, a1, a2, a3};
        *(f4*)(outp + (size_t)o * (HH * WW)) = res;
    }
}

extern "C" void kernel_launch(void* const* d_in, const int* in_sizes, int n_in,
                              void* d_out, int out_size, void* d_ws, size_t ws_size,
                              hipStream_t stream) {
    const float* x    = (const float*)d_in[0];
    const float* Wg   = (const float*)d_in[1];
    const float* bias = (const float*)d_in[2];
    float* out = (float*)d_out;

    dim3 block(128, 2, 1);
    dim3 grid(1, 256, 16);
    hipLaunchKernelGGL(pointconv_kernel, grid, block, 0, stream, x, Wg, bias, out);
}